// Round 7
// baseline (137.933 us; speedup 1.0000x reference)
//
#include <hip/hip_runtime.h>
#include <hip/hip_bf16.h>

// KroneckerProjection: out = X @ kron(A,B), factored.
//   Step 1 (fp32 VALU, verified): T[m][j][k] = sum_i x[m][i*16+k]*A[i][j]
//   Step 2 (bf16 MFMA, verified):  out[m][j*512+l] = sum_k T[m][j][k]*B[k][l]
// r7 = r6 with the D-transpose tile halved (two 64-col passes per j) so
// LDS = 34.6 KB < 40 KB -> 4 blocks/CU -> the whole 1024-block grid is
// co-resident (r6's 51 KB allowed only 3/CU -> 256-block serial tail).
// NT stores kept (r6's proven win). Arithmetic identical to r5/r6.

#define DIN   2048
#define DOUT  8192
#define TS    268      // T_lds row stride (dwords): 16B-aligned, bank-spread
#define TRS   68       // transpose tile row stride (dwords): 16B-aligned, ≡4 mod 32

typedef __attribute__((ext_vector_type(8))) short bf16x8;
typedef __attribute__((ext_vector_type(4))) float f32x4;

__device__ __forceinline__ short f2bf(float f) {
    __hip_bfloat16 h = __float2bfloat16(f);   // RNE
    short s;
    __builtin_memcpy(&s, &h, 2);
    return s;
}

__global__ __launch_bounds__(256, 4)
void kron_mfma4_kernel(const float* __restrict__ x,
                       const float* __restrict__ A,
                       const float* __restrict__ B,
                       float* __restrict__ out)
{
    __shared__ __align__(16) float T_lds[16 * TS];        // 17.2 KiB
    __shared__ __align__(16) float trans[4][16 * TRS];    // 17.4 KiB

    const int t    = threadIdx.x;
    const int w    = t >> 6;                  // wave 0..3
    const int lane = t & 63;
    const int row0 = blockIdx.x * 16;

    // ---- Step 1: rows row0+4w..+3, lane=(r,k) — verified fp32 path
    const int r = lane >> 4, k = lane & 15;
    {
        float T[16];
#pragma unroll
        for (int j = 0; j < 16; ++j) T[j] = 0.f;

        const float* xr = x + (size_t)(row0 + 4 * w + r) * DIN + k;
#pragma unroll 8
        for (int i = 0; i < 128; ++i) {
            const float xv = xr[i * 16];      // coalesced 64B segments
            const float* Ar = A + i * 16;     // uniform -> s_load
#pragma unroll
            for (int j = 0; j < 16; ++j) T[j] = fmaf(xv, Ar[j], T[j]);
        }
        float* Tm = T_lds + (4 * w + r) * TS + k;
#pragma unroll
        for (int j = 0; j < 16; ++j) Tm[j * 16] = T[j];
    }

    // ---- B-frags (verified): elem e = B[k=q*8+e][w*128 + c*16 + n]; q>=2 zero
    const int q = lane >> 4;
    const int n = lane & 15;
    bf16x8 bfrag[8];
#pragma unroll
    for (int c = 0; c < 8; ++c) {
        bf16x8 f = (bf16x8)0;
        if (q < 2) {
            const float* Bp = B + (size_t)(q * 8) * 512 + w * 128 + c * 16 + n;
#pragma unroll
            for (int e = 0; e < 8; ++e) f[e] = f2bf(Bp[(size_t)e * 512]);
        }
        bfrag[c] = f;
    }

    __syncthreads();   // all T rows visible to all waves

    float* tw = trans[w];
    const int g  = lane >> 4;                 // 0..3: row group for store-back
    const int c4 = (lane & 15) * 4;           // col offset for store-back

    // ---- Step 2 main loop over j
#pragma unroll 2
    for (int j = 0; j < 16; ++j) {
        // afrag on demand (verified layout): elem e = U[m=n][k=q*8+e]; q>=2 zero
        bf16x8 af = (bf16x8)0;
        if (q < 2) {
            const float* Tp = T_lds + n * TS + j * 16 + q * 8;
            float4 t0 = *(const float4*)(Tp);
            float4 t1 = *(const float4*)(Tp + 4);
            af[0] = f2bf(t0.x); af[1] = f2bf(t0.y);
            af[2] = f2bf(t0.z); af[3] = f2bf(t0.w);
            af[4] = f2bf(t1.x); af[5] = f2bf(t1.y);
            af[6] = f2bf(t1.z); af[7] = f2bf(t1.w);
        }

        // two 64-col half-passes through the small per-wave transpose tile
#pragma unroll
        for (int ch = 0; ch < 2; ++ch) {
            f32x4 d[4];
#pragma unroll
            for (int c = 0; c < 4; ++c) {
                f32x4 z = {0.f, 0.f, 0.f, 0.f};
                d[c] = __builtin_amdgcn_mfma_f32_16x16x32_bf16(
                           af, bfrag[ch * 4 + c], z, 0, 0, 0);
            }
            // D(lane(q,n), reg p) = out[row=q*4+p][col=c*16+n] -> transpose
            // into LDS (write banks: 2-way only = free)
#pragma unroll
            for (int c = 0; c < 4; ++c) {
                float* tp = tw + c * 16 + n;
                tp[(q * 4 + 0) * TRS] = d[c][0];
                tp[(q * 4 + 1) * TRS] = d[c][1];
                tp[(q * 4 + 2) * TRS] = d[c][2];
                tp[(q * 4 + 3) * TRS] = d[c][3];
            }
            // read back coalesced, NT store: 4 instrs x 256B contiguous rows
            float* ob = out + (size_t)row0 * DOUT + j * 512 + w * 128
                        + ch * 64 + c4;
#pragma unroll
            for (int rp = 0; rp < 4; ++rp) {
                const int row = rp * 4 + g;
                f32x4 v = *(const f32x4*)(tw + row * TRS + c4);
                __builtin_nontemporal_store(v, (f32x4*)(ob + (size_t)row * DOUT));
            }
        }
    }
}

extern "C" void kernel_launch(void* const* d_in, const int* in_sizes, int n_in,
                              void* d_out, int out_size, void* d_ws, size_t ws_size,
                              hipStream_t stream) {
    const float* x = (const float*)d_in[0];
    const float* A = (const float*)d_in[1];
    const float* B = (const float*)d_in[2];
    float* out = (float*)d_out;

    const int nrows = in_sizes[0] / DIN;      // 16384
    const int grid  = nrows / 16;             // 1024 blocks = 4/CU co-resident

    kron_mfma4_kernel<<<dim3(grid), dim3(256), 0, stream>>>(x, A, B, out);
}

// Round 8
// 131.739 us; speedup vs baseline: 1.0470x; 1.0470x over previous
//
#include <hip/hip_runtime.h>
#include <hip/hip_bf16.h>

// KroneckerProjection: out = X @ kron(A,B), factored.
//   Step 1 (fp32 VALU, verified): T[m][j][k] = sum_i x[m][i*16+k]*A[i][j]
//   Step 2 (bf16 MFMA, verified):  out[m][j*512+l] = sum_k T[m][j][k]*B[k][l]
// r8 = r6 with a 4-blocks/CU occupancy package (r6's tail was 3 blocks/CU vs
// a 4/CU grid):
//  - afrag built ONCE for all 16 j (64 VGPRs) -> T_lds dead after prologue
//  - T_lds UNIONED with the transpose tiles -> LDS 51 -> 33.8 KB -> 4 blk/CU
//  - j-loop fully unrolled (afrag compile-time indexed, no scratch)
//  - register budget ~115 < 128 -> launch_bounds(256,4) without spill
// Store path byte-identical to r6: per-wave LDS transpose, 512B-contiguous
// nontemporal float4 stores (r6's proven +15us win).

#define DIN   2048
#define DOUT  8192
#define TS    268      // T region row stride (dwords): 16B-aligned, bank-spread
#define TRS   132      // transpose tile row stride (dwords): 16B-aligned

typedef __attribute__((ext_vector_type(8))) short bf16x8;
typedef __attribute__((ext_vector_type(4))) float f32x4;

__device__ __forceinline__ short f2bf(float f) {
    __hip_bfloat16 h = __float2bfloat16(f);   // RNE
    short s;
    __builtin_memcpy(&s, &h, 2);
    return s;
}

__global__ __launch_bounds__(256, 4)
void kron_mfma5_kernel(const float* __restrict__ x,
                       const float* __restrict__ A,
                       const float* __restrict__ B,
                       float* __restrict__ out)
{
    // Union: [0 .. 16*TS) = T staging (prologue only); whole buffer = 4 per-
    // wave transpose tiles (main loop). 8448 dwords = 33.8 KiB.
    __shared__ __align__(16) float shmem[4 * 16 * TRS];

    const int t    = threadIdx.x;
    const int w    = t >> 6;                  // wave 0..3
    const int lane = t & 63;
    const int row0 = blockIdx.x * 16;

    // ---- Step 1: rows row0+4w..+3, lane=(r,k) — verified fp32 path
    const int r = lane >> 4, k = lane & 15;
    {
        float T[16];
#pragma unroll
        for (int j = 0; j < 16; ++j) T[j] = 0.f;

        const float* xr = x + (size_t)(row0 + 4 * w + r) * DIN + k;
#pragma unroll 8
        for (int i = 0; i < 128; ++i) {
            const float xv = xr[i * 16];      // coalesced 64B segments
            const float* Ar = A + i * 16;     // uniform -> s_load
#pragma unroll
            for (int j = 0; j < 16; ++j) T[j] = fmaf(xv, Ar[j], T[j]);
        }
        float* Tm = shmem + (4 * w + r) * TS + k;
#pragma unroll
        for (int j = 0; j < 16; ++j) Tm[j * 16] = T[j];
    }

    // ---- B-frags (verified): elem e = B[k=q*8+e][w*128 + c*16 + n]; q>=2 zero
    const int q = lane >> 4;
    const int n = lane & 15;
    bf16x8 bfrag[8];
#pragma unroll
    for (int c = 0; c < 8; ++c) {
        bf16x8 f = (bf16x8)0;
        if (q < 2) {
            const float* Bp = B + (size_t)(q * 8) * 512 + w * 128 + c * 16 + n;
#pragma unroll
            for (int e = 0; e < 8; ++e) f[e] = f2bf(Bp[(size_t)e * 512]);
        }
        bfrag[c] = f;
    }

    __syncthreads();   // all T rows visible to all waves

    // ---- A-frags for ALL j, once (verified layout): elem e = U[m=n][k=q*8+e]
    bf16x8 afrag[16];
#pragma unroll
    for (int j = 0; j < 16; ++j) {
        bf16x8 f = (bf16x8)0;
        if (q < 2) {
            const float* Tp = shmem + n * TS + j * 16 + q * 8;
            float4 t0 = *(const float4*)(Tp);
            float4 t1 = *(const float4*)(Tp + 4);
            f[0] = f2bf(t0.x); f[1] = f2bf(t0.y);
            f[2] = f2bf(t0.z); f[3] = f2bf(t0.w);
            f[4] = f2bf(t1.x); f[5] = f2bf(t1.y);
            f[6] = f2bf(t1.z); f[7] = f2bf(t1.w);
        }
        afrag[j] = f;
    }

    __syncthreads();   // T region dead -> safe to reuse as transpose tiles

    float* tw = shmem + w * (16 * TRS);       // per-wave tile (wave-private)
    const int rrow = (lane >> 5);             // 0/1: row within pair
    const int c4   = (lane & 31) * 4;         // col offset within 128-col chunk

    // ---- Step 2: fully unrolled j-loop (afrag indices compile-time)
#pragma unroll
    for (int j = 0; j < 16; ++j) {
        // MFMA per 16-col chunk; D(lane(q,n), reg p) = out[row=q*4+p][col=c*16+n]
        // -> transpose into LDS tile (2-way write banks = free)
#pragma unroll
        for (int c = 0; c < 8; ++c) {
            f32x4 d = {0.f, 0.f, 0.f, 0.f};
            d = __builtin_amdgcn_mfma_f32_16x16x32_bf16(afrag[j], bfrag[c], d,
                                                        0, 0, 0);
            float* tp = tw + c * 16 + n;
            tp[(q * 4 + 0) * TRS] = d[0];
            tp[(q * 4 + 1) * TRS] = d[1];
            tp[(q * 4 + 2) * TRS] = d[2];
            tp[(q * 4 + 3) * TRS] = d[3];
        }

        // read back coalesced; NT stores: 8 instrs x 512B contiguous (as r6)
        float* ob = out + (size_t)row0 * DOUT + j * 512 + w * 128 + c4;
#pragma unroll
        for (int rp = 0; rp < 8; ++rp) {
            const int row = 2 * rp + rrow;
            f32x4 v = *(const f32x4*)(tw + row * TRS + c4);
            __builtin_nontemporal_store(v, (f32x4*)(ob + (size_t)row * DOUT));
        }
    }
}

extern "C" void kernel_launch(void* const* d_in, const int* in_sizes, int n_in,
                              void* d_out, int out_size, void* d_ws, size_t ws_size,
                              hipStream_t stream) {
    const float* x = (const float*)d_in[0];
    const float* A = (const float*)d_in[1];
    const float* B = (const float*)d_in[2];
    float* out = (float*)d_out;

    const int nrows = in_sizes[0] / DIN;      // 16384
    const int grid  = nrows / 16;             // 1024 blocks = 4/CU co-resident

    kron_mfma5_kernel<<<dim3(grid), dim3(256), 0, stream>>>(x, A, B, out);
}